// Round 6
// baseline (117.848 us; speedup 1.0000x reference)
//
#include <hip/hip_runtime.h>
#include <hip/hip_bf16.h>

// MultiHeadLiftLayer:
//   y0 = x0 @ W[:128]  (per-node, 50000x8)   -> table in d_ws
//   y1 = x0 @ W[128:]  (per-node, 50000x8)   -> table in d_ws (offset)
//   out[e, 0:8]  = relu(y0[src[e]] + y1[tgt[e]])
//   out[e, 8:72] = x_1[e]                     // (625000, 72) f32
//
// Edge kernel (R6): burst-homogeneous structure. Per 128-edge tile:
//   (a) dense coalesced x1 reads -> strided writes into an 18-f4v-stride
//       LDS tile (columns 2..17); adj + y gathers + relu fill columns 0..1.
//   (b) barrier.
//   (c) PURE STORE BURST: dense LDS -> dense global, no index math, no
//       divergence, no interleaved global loads.
// Rationale: R1/R2/R5 all ~100us regardless of gather scheduling -> gathers
// are not the limiter; the fine-grained read/write interleave in each wave's
// issue stream is the suspect. Fills do 7 TB/s pure-write; copy ubench 6.3
// TB/s on homogeneous streams.

typedef float f4v __attribute__((ext_vector_type(4)));

#define NUM_NODES 50000
#define C0 128
#define HEADS 8
#define NODES_PER_BLK 16
#define XS_STRIDE 132            // 128 + 4 pad
#define TILE 128                 // edges per tile (36 KB LDS tile)
#define EGRID 2048               // 8 blocks/CU... 4 resident (LDS-limited)

__global__ __launch_bounds__(256) void node_proj_kernel(
    const float* __restrict__ x0, const float* __restrict__ W,
    float* __restrict__ y, int num_nodes)
{
    __shared__ float Ws[2 * C0 * HEADS];          // 8 KB
    __shared__ float xs[NODES_PER_BLK * XS_STRIDE];

    for (int i = threadIdx.x; i < 2 * C0 * HEADS; i += 256) Ws[i] = W[i];

    const int nodeBase = blockIdx.x * NODES_PER_BLK;
    for (int i = threadIdx.x; i < NODES_PER_BLK * C0; i += 256) {
        int r = i >> 7;
        int c = i & (C0 - 1);
        int n = nodeBase + r;
        xs[r * XS_STRIDE + c] = (n < num_nodes) ? x0[n * C0 + c] : 0.f;
    }
    __syncthreads();

    const int local = threadIdx.x >> 4;
    const int slot  = threadIdx.x & 15;   // half*8 + h
    const int half  = slot >> 3;
    const int h     = slot & 7;

    const float* xr = &xs[local * XS_STRIDE];
    const float* Wr = &Ws[half * C0 * HEADS + h];

    float acc = 0.f;
    #pragma unroll 8
    for (int c = 0; c < C0; ++c)
        acc = fmaf(xr[c], Wr[c * HEADS], acc);

    // y0 table: y[n*8 + h]; y1 table: y[NUM_NODES*8 + n*8 + h]
    const int n = nodeBase + local;
    if (n < num_nodes) y[half * (NUM_NODES * HEADS) + n * HEADS + h] = acc;
}

static __device__ __forceinline__ f4v relu4(f4v a, f4v b) {
    f4v r;
    r.x = fmaxf(a.x + b.x, 0.f);
    r.y = fmaxf(a.y + b.y, 0.f);
    r.z = fmaxf(a.z + b.z, 0.f);
    r.w = fmaxf(a.w + b.w, 0.f);
    return r;
}

__global__ __launch_bounds__(256) void edge_out_kernel(
    const float* __restrict__ y, const float* __restrict__ x1,
    const int* __restrict__ adj, float* __restrict__ out, int E, int ntiles)
{
    __shared__ f4v tile[TILE * 18];   // 36 KB: full 18-wide output rows

    const int tid = threadIdx.x;
    const f4v* __restrict__ y0v = (const f4v*)y;           // 2 f4 per node
    const f4v* __restrict__ y1v = y0v + 2 * NUM_NODES;
    const f4v* __restrict__ x1v = (const f4v*)x1;          // 16 f4 per edge
    f4v* __restrict__ outv = (f4v*)out;                    // 18 f4 per edge

    // balanced contiguous tile range per block (no 2-vs-3 tail skew)
    const int t0 = (int)(((long long)blockIdx.x * ntiles) / EGRID);
    const int t1 = (int)(((long long)(blockIdx.x + 1) * ntiles) / EGRID);

    for (int t = t0; t < t1; ++t) {
        const int base  = t * TILE;
        const int nrows = (E - base < TILE) ? (E - base) : TILE;

        // adj first (longest dependency chain: adj -> y gather)
        int s = 0, tt = 0;
        const bool ge = (tid < nrows);
        if (ge) { s = adj[base + tid]; tt = adj[E + base + tid]; }

        // dense coalesced x1 reads -> strided LDS writes (cols 2..17)
        const f4v* __restrict__ x1b = x1v + (size_t)base * 16;
        const int n16 = nrows * 16;
        #pragma unroll
        for (int k = 0; k < 8; ++k) {
            const int g = k * 256 + tid;
            if (g < n16) {
                const f4v v = x1b[g];
                tile[(g >> 4) * 18 + (g & 15) + 2] = v;
            }
        }

        // y gathers + relu -> LDS head slots (cols 0..1)
        if (ge) {
            const f4v h0 = relu4(y0v[s * 2],     y1v[tt * 2]);
            const f4v h1 = relu4(y0v[s * 2 + 1], y1v[tt * 2 + 1]);
            tile[tid * 18]     = h0;
            tile[tid * 18 + 1] = h1;
        }
        __syncthreads();

        // PURE STORE BURST: dense LDS -> dense global, nothing else
        const int n4 = nrows * 18;
        f4v* __restrict__ outb = outv + (size_t)base * 18;
        #pragma unroll
        for (int k = 0; k < 9; ++k) {
            const int i = k * 256 + tid;
            if (i < n4) outb[i] = tile[i];
        }
        __syncthreads();   // protect LDS before next tile overwrites
    }
}

extern "C" void kernel_launch(void* const* d_in, const int* in_sizes, int n_in,
                              void* d_out, int out_size, void* d_ws, size_t ws_size,
                              hipStream_t stream) {
    const float* x0  = (const float*)d_in[0];
    const int*   adj = (const int*)d_in[1];   // JAX demotes int64->int32
    const float* x1  = (const float*)d_in[2];
    const float* W   = (const float*)d_in[3];
    float* out = (float*)d_out;
    float* y   = (float*)d_ws;                // 2 * 50000*8 floats = 3.2 MB

    const int E = in_sizes[1] / 2;            // 625000
    const int ntiles = (E + TILE - 1) / TILE; // 4883

    {
        dim3 grid((NUM_NODES + NODES_PER_BLK - 1) / NODES_PER_BLK);
        node_proj_kernel<<<grid, 256, 0, stream>>>(x0, W, y, NUM_NODES);
    }
    {
        edge_out_kernel<<<EGRID, 256, 0, stream>>>(y, x1, adj, out, E, ntiles);
    }
}

// Round 7
// 114.333 us; speedup vs baseline: 1.0307x; 1.0307x over previous
//
#include <hip/hip_runtime.h>
#include <hip/hip_bf16.h>

// MultiHeadLiftLayer, R7: full role separation in time.
//   K1 node_proj: y0/y1 tables (per-node projection)      -> d_ws[0..3.2MB)
//   K2 head:      hd[e] = {relu(y0[s]+y1[t])} dense 20 MB -> d_ws[3.2MB..)
//   K3 merge:     out[i] = (j<2 ? hd[e*2+j] : x1[e*16+j-2])  pure 3-stream
//                 merge-copy: one load + one store per f4, no LDS, no
//                 barriers, no gathers, x4 unrolled for 4 KB/wave in flight.
// Rationale: R1/R2/R5/R6 edge structures all stuck at ~3-4 TB/s regardless
// of schedule; K3 is the closest legal analog of the 6.3 TB/s copy ubench.
// If K3 also runs ~3 TB/s, that's the pattern roofline (declare next round).

typedef float f4v __attribute__((ext_vector_type(4)));

#define NUM_NODES 50000
#define C0 128
#define HEADS 8
#define NODES_PER_BLK 16
#define XS_STRIDE 132            // 128 + 4 pad
#define MGRID 2048               // merge blocks
#define MBLK 256

__global__ __launch_bounds__(256) void node_proj_kernel(
    const float* __restrict__ x0, const float* __restrict__ W,
    float* __restrict__ y, int num_nodes)
{
    __shared__ float Ws[2 * C0 * HEADS];          // 8 KB
    __shared__ float xs[NODES_PER_BLK * XS_STRIDE];

    for (int i = threadIdx.x; i < 2 * C0 * HEADS; i += 256) Ws[i] = W[i];

    const int nodeBase = blockIdx.x * NODES_PER_BLK;
    for (int i = threadIdx.x; i < NODES_PER_BLK * C0; i += 256) {
        int r = i >> 7;
        int c = i & (C0 - 1);
        int n = nodeBase + r;
        xs[r * XS_STRIDE + c] = (n < num_nodes) ? x0[n * C0 + c] : 0.f;
    }
    __syncthreads();

    const int local = threadIdx.x >> 4;
    const int slot  = threadIdx.x & 15;   // half*8 + h
    const int half  = slot >> 3;
    const int h     = slot & 7;

    const float* xr = &xs[local * XS_STRIDE];
    const float* Wr = &Ws[half * C0 * HEADS + h];

    float acc = 0.f;
    #pragma unroll 8
    for (int c = 0; c < C0; ++c)
        acc = fmaf(xr[c], Wr[c * HEADS], acc);

    // y0 table: y[n*8 + h]; y1 table: y[NUM_NODES*8 + n*8 + h]
    const int n = nodeBase + local;
    if (n < num_nodes) y[half * (NUM_NODES * HEADS) + n * HEADS + h] = acc;
}

static __device__ __forceinline__ f4v relu4(f4v a, f4v b) {
    f4v r;
    r.x = fmaxf(a.x + b.x, 0.f);
    r.y = fmaxf(a.y + b.y, 0.f);
    r.z = fmaxf(a.z + b.z, 0.f);
    r.w = fmaxf(a.w + b.w, 0.f);
    return r;
}

// K2: gathers only. Dense sequential 32B stores to hd. y tables are
// L2/L3-resident (3.2 MB), adj reads coalesced.
__global__ __launch_bounds__(256) void head_kernel(
    const float* __restrict__ y, const int* __restrict__ adj,
    float* __restrict__ hd, int E)
{
    const int e = blockIdx.x * 256 + threadIdx.x;
    if (e >= E) return;
    const f4v* __restrict__ y0v = (const f4v*)y;          // 2 f4 per node
    const f4v* __restrict__ y1v = y0v + 2 * NUM_NODES;
    f4v* __restrict__ hdv = (f4v*)hd;                     // 2 f4 per edge

    const int s = adj[e];
    const int t = adj[E + e];
    const f4v h0 = relu4(y0v[s * 2],     y1v[t * 2]);
    const f4v h1 = relu4(y0v[s * 2 + 1], y1v[t * 2 + 1]);
    hdv[e * 2]     = h0;
    hdv[e * 2 + 1] = h1;
}

// K3: pure 3-stream merge-copy. One load + one store per f4v item.
static __device__ __forceinline__ f4v merge_ld(
    const f4v* __restrict__ hdv, const f4v* __restrict__ x1v, int i)
{
    const int e = i / 18;                  // compiler magic-mul
    const int j = i - e * 18;
    const f4v* p = (j < 2) ? (hdv + (e * 2 + j)) : (x1v + (e * 16 + (j - 2)));
    return *p;
}

__global__ __launch_bounds__(MBLK) void merge_kernel(
    const float* __restrict__ hd, const float* __restrict__ x1,
    float* __restrict__ out, int total)
{
    const f4v* __restrict__ hdv = (const f4v*)hd;
    const f4v* __restrict__ x1v = (const f4v*)x1;
    f4v* __restrict__ outv = (f4v*)out;

    const int stride = MGRID * MBLK;       // 524288
    int i = blockIdx.x * MBLK + threadIdx.x;

    // main: 4 independent loads in flight per thread
    for (; i + 3 * stride < total; i += 4 * stride) {
        const f4v v0 = merge_ld(hdv, x1v, i);
        const f4v v1 = merge_ld(hdv, x1v, i + stride);
        const f4v v2 = merge_ld(hdv, x1v, i + 2 * stride);
        const f4v v3 = merge_ld(hdv, x1v, i + 3 * stride);
        outv[i]              = v0;
        outv[i + stride]     = v1;
        outv[i + 2 * stride] = v2;
        outv[i + 3 * stride] = v3;
    }
    for (; i < total; i += stride)
        outv[i] = merge_ld(hdv, x1v, i);
}

extern "C" void kernel_launch(void* const* d_in, const int* in_sizes, int n_in,
                              void* d_out, int out_size, void* d_ws, size_t ws_size,
                              hipStream_t stream) {
    const float* x0  = (const float*)d_in[0];
    const int*   adj = (const int*)d_in[1];   // JAX demotes int64->int32
    const float* x1  = (const float*)d_in[2];
    const float* W   = (const float*)d_in[3];
    float* out = (float*)d_out;
    float* y   = (float*)d_ws;                        // 800000 floats = 3.2 MB
    float* hd  = (float*)d_ws + 2 * NUM_NODES * HEADS;// 1.25M*8 floats = 20 MB

    const int E = in_sizes[1] / 2;            // 625000

    {
        dim3 grid((NUM_NODES + NODES_PER_BLK - 1) / NODES_PER_BLK);
        node_proj_kernel<<<grid, 256, 0, stream>>>(x0, W, y, NUM_NODES);
    }
    {
        dim3 grid((E + 255) / 256);           // 2442
        head_kernel<<<grid, 256, 0, stream>>>(y, adj, hd, E);
    }
    {
        const int total = E * 18;             // 11,250,000 f4v
        merge_kernel<<<MGRID, MBLK, 0, stream>>>(hd, x1, out, total);
    }
}

// Round 8
// 90.284 us; speedup vs baseline: 1.3053x; 1.2664x over previous
//
#include <hip/hip_runtime.h>
#include <hip/hip_bf16.h>

// MultiHeadLiftLayer, R8: R1's flat kernel (best measured, 93us edge) with
// NONTEMPORAL out stores. out is write-once and never re-read; streaming it
// past L3 keeps x1 (160 MB) + y + adj resident in the 256 MB Infinity Cache
// across graph replays (R2/R6 replays already showed partial x1 retention:
// FETCH 110-130 MB < 160 MB compulsory). nt is RMW-safe here because every
// 128B line of out is written entirely by one wave-instruction (flat i ->
// 1KB-aligned chunks per wave), unlike R4's two-writer split lines.

typedef float f4v __attribute__((ext_vector_type(4)));

#define NUM_NODES 50000
#define C0 128
#define HEADS 8
#define NODES_PER_BLK 16
#define XS_STRIDE 132            // 128 + 4 pad

__global__ __launch_bounds__(256) void node_proj_kernel(
    const float* __restrict__ x0, const float* __restrict__ W,
    float* __restrict__ y, int num_nodes)
{
    __shared__ float Ws[2 * C0 * HEADS];          // 8 KB
    __shared__ float xs[NODES_PER_BLK * XS_STRIDE];

    for (int i = threadIdx.x; i < 2 * C0 * HEADS; i += 256) Ws[i] = W[i];

    const int nodeBase = blockIdx.x * NODES_PER_BLK;
    for (int i = threadIdx.x; i < NODES_PER_BLK * C0; i += 256) {
        int r = i >> 7;
        int c = i & (C0 - 1);
        int n = nodeBase + r;
        xs[r * XS_STRIDE + c] = (n < num_nodes) ? x0[n * C0 + c] : 0.f;
    }
    __syncthreads();

    const int local = threadIdx.x >> 4;
    const int slot  = threadIdx.x & 15;   // half*8 + h
    const int half  = slot >> 3;
    const int h     = slot & 7;

    const float* xr = &xs[local * XS_STRIDE];
    const float* Wr = &Ws[half * C0 * HEADS + h];

    float acc = 0.f;
    #pragma unroll 8
    for (int c = 0; c < C0; ++c)
        acc = fmaf(xr[c], Wr[c * HEADS], acc);

    // y0 table: y[n*8 + h]; y1 table: y[NUM_NODES*8 + n*8 + h]
    const int n = nodeBase + local;
    if (n < num_nodes) y[half * (NUM_NODES * HEADS) + n * HEADS + h] = acc;
}

static __device__ __forceinline__ f4v relu4(f4v a, f4v b) {
    f4v r;
    r.x = fmaxf(a.x + b.x, 0.f);
    r.y = fmaxf(a.y + b.y, 0.f);
    r.z = fmaxf(a.z + b.z, 0.f);
    r.w = fmaxf(a.w + b.w, 0.f);
    return r;
}

// Flat over E*18 f4v items. j<2: gather y0[src]/y1[tgt], relu. j>=2: copy x1.
// Stores nontemporal (full-line per wave, no L3 allocation).
__global__ __launch_bounds__(256) void edge_out_kernel(
    const float* __restrict__ y, const float* __restrict__ x1,
    const int* __restrict__ adj, float* __restrict__ out, int E)
{
    const f4v* __restrict__ y0v = (const f4v*)y;           // 2 f4 per node
    const f4v* __restrict__ y1v = y0v + 2 * NUM_NODES;
    const f4v* __restrict__ x1v = (const f4v*)x1;          // 16 f4 per edge
    f4v* __restrict__ outv = (f4v*)out;                    // 18 f4 per edge

    const int total = E * 18;
    for (int i = blockIdx.x * blockDim.x + threadIdx.x; i < total;
         i += gridDim.x * blockDim.x) {
        const int e = i / 18;              // magic-mul
        const int j = i - e * 18;
        f4v v;
        if (j >= 2) {
            v = x1v[e * 16 + (j - 2)];
        } else {
            const int s = adj[e];
            const int t = adj[E + e];
            v = relu4(y0v[s * 2 + j], y1v[t * 2 + j]);
        }
        __builtin_nontemporal_store(v, &outv[i]);
    }
}

extern "C" void kernel_launch(void* const* d_in, const int* in_sizes, int n_in,
                              void* d_out, int out_size, void* d_ws, size_t ws_size,
                              hipStream_t stream) {
    const float* x0  = (const float*)d_in[0];
    const int*   adj = (const int*)d_in[1];   // JAX demotes int64->int32
    const float* x1  = (const float*)d_in[2];
    const float* W   = (const float*)d_in[3];
    float* out = (float*)d_out;
    float* y   = (float*)d_ws;                // 2 * 50000*8 floats = 3.2 MB

    const int E = in_sizes[1] / 2;            // 625000

    {
        dim3 grid((NUM_NODES + NODES_PER_BLK - 1) / NODES_PER_BLK);
        node_proj_kernel<<<grid, 256, 0, stream>>>(x0, W, y, NUM_NODES);
    }
    {
        const int total4 = E * 18;
        int blocks = (total4 + 255) / 256;
        if (blocks > 8192) blocks = 8192;
        edge_out_kernel<<<blocks, 256, 0, stream>>>(y, x1, adj, out, E);
    }
}

// Round 9
// 83.248 us; speedup vs baseline: 1.4156x; 1.0845x over previous
//
#include <hip/hip_runtime.h>
#include <hip/hip_bf16.h>

// MultiHeadLiftLayer, R9 = R8 edge (best: flat + nt stores, ~80us) +
// vectorized node_proj:
//   - f4 (dwordx4) staging for W and x0, f4 LDS reads for x (ds_read_b128)
//   - 32 nodes/block: each W LDS read shared by 2 accumulators; W global
//     re-fetch halved (3125 -> 1563 blocks x 8 KB)
// Edge-kernel history: 6 structures all land at ~3.7-4.4 TB/s mixed R/W
// (flat 93 / two-phase 100.8 / pipelined ~100 / LDS-burst 103.5 / merge ~90 /
// flat+nt ~80us) -> memory-system bound; flat+nt is the ceiling so far.

typedef float f4v __attribute__((ext_vector_type(4)));

#define NUM_NODES 50000
#define C0 128
#define HEADS 8
#define NPB 32                   // nodes per block (node_proj)
#define XSP 33                   // 32 f4 + 1 pad (f4 units)

__global__ __launch_bounds__(256) void node_proj_kernel(
    const float* __restrict__ x0, const float* __restrict__ W,
    float* __restrict__ y, int num_nodes)
{
    __shared__ float Ws[2 * C0 * HEADS];   // 8 KB, W row-major [256][8]
    __shared__ f4v   xs4[NPB * XSP];       // 16.9 KB, padded rows of 32 f4

    // stage W via f4 (512 f4, 2 per thread)
    {
        const f4v* __restrict__ Wv = (const f4v*)W;
        f4v* Wsv = (f4v*)Ws;
        Wsv[threadIdx.x]       = Wv[threadIdx.x];
        Wsv[threadIdx.x + 256] = Wv[threadIdx.x + 256];
    }

    // stage 32 rows of x0 via f4 (1024 f4, 4 per thread, coalesced)
    const int nodeBase = blockIdx.x * NPB;
    const f4v* __restrict__ x0v = (const f4v*)x0;   // 32 f4 per node row
    #pragma unroll
    for (int k = 0; k < 4; ++k) {
        const int idx = k * 256 + threadIdx.x;
        const int r   = idx >> 5;          // local node
        const int c   = idx & 31;          // f4 column
        const int n   = nodeBase + r;
        f4v v = {0.f, 0.f, 0.f, 0.f};
        if (n < num_nodes) v = x0v[n * 32 + c];
        xs4[r * XSP + c] = v;
    }
    __syncthreads();

    const int slot  = threadIdx.x & 15;    // half*8 + h
    const int local = threadIdx.x >> 4;    // 0..15; also handles local+16
    const int half  = slot >> 3;
    const int h     = slot & 7;

    const f4v* xr0 = &xs4[local * XSP];
    const f4v* xr1 = &xs4[(local + 16) * XSP];
    const float* Wb = &Ws[half * C0 * HEADS + h];   // + c*8 per element

    float acc0 = 0.f, acc1 = 0.f;
    #pragma unroll 4
    for (int cq = 0; cq < 32; ++cq) {
        const f4v xq0 = xr0[cq];
        const f4v xq1 = xr1[cq];
        #pragma unroll
        for (int k = 0; k < 4; ++k) {
            const float w = Wb[(cq * 4 + k) * HEADS];   // shared by both nodes
            acc0 = fmaf(xq0[k], w, acc0);
            acc1 = fmaf(xq1[k], w, acc1);
        }
    }

    // y0 table: y[n*8 + h]; y1 table: y[NUM_NODES*8 + n*8 + h]
    const int n0 = nodeBase + local;
    const int n1 = n0 + 16;
    if (n0 < num_nodes) y[half * (NUM_NODES * HEADS) + n0 * HEADS + h] = acc0;
    if (n1 < num_nodes) y[half * (NUM_NODES * HEADS) + n1 * HEADS + h] = acc1;
}

static __device__ __forceinline__ f4v relu4(f4v a, f4v b) {
    f4v r;
    r.x = fmaxf(a.x + b.x, 0.f);
    r.y = fmaxf(a.y + b.y, 0.f);
    r.z = fmaxf(a.z + b.z, 0.f);
    r.w = fmaxf(a.w + b.w, 0.f);
    return r;
}

// Flat over E*18 f4v items. j<2: gather y0[src]/y1[tgt], relu. j>=2: copy x1.
// Stores nontemporal (full-line per wave, no L3 allocation). UNCHANGED from R8.
__global__ __launch_bounds__(256) void edge_out_kernel(
    const float* __restrict__ y, const float* __restrict__ x1,
    const int* __restrict__ adj, float* __restrict__ out, int E)
{
    const f4v* __restrict__ y0v = (const f4v*)y;           // 2 f4 per node
    const f4v* __restrict__ y1v = y0v + 2 * NUM_NODES;
    const f4v* __restrict__ x1v = (const f4v*)x1;          // 16 f4 per edge
    f4v* __restrict__ outv = (f4v*)out;                    // 18 f4 per edge

    const int total = E * 18;
    for (int i = blockIdx.x * blockDim.x + threadIdx.x; i < total;
         i += gridDim.x * blockDim.x) {
        const int e = i / 18;              // magic-mul
        const int j = i - e * 18;
        f4v v;
        if (j >= 2) {
            v = x1v[e * 16 + (j - 2)];
        } else {
            const int s = adj[e];
            const int t = adj[E + e];
            v = relu4(y0v[s * 2 + j], y1v[t * 2 + j]);
        }
        __builtin_nontemporal_store(v, &outv[i]);
    }
}

extern "C" void kernel_launch(void* const* d_in, const int* in_sizes, int n_in,
                              void* d_out, int out_size, void* d_ws, size_t ws_size,
                              hipStream_t stream) {
    const float* x0  = (const float*)d_in[0];
    const int*   adj = (const int*)d_in[1];   // JAX demotes int64->int32
    const float* x1  = (const float*)d_in[2];
    const float* W   = (const float*)d_in[3];
    float* out = (float*)d_out;
    float* y   = (float*)d_ws;                // 2 * 50000*8 floats = 3.2 MB

    const int E = in_sizes[1] / 2;            // 625000

    {
        dim3 grid((NUM_NODES + NPB - 1) / NPB);   // 1563
        node_proj_kernel<<<grid, 256, 0, stream>>>(x0, W, y, NUM_NODES);
    }
    {
        const int total4 = E * 18;
        int blocks = (total4 + 255) / 256;
        if (blocks > 8192) blocks = 8192;
        edge_out_kernel<<<blocks, 256, 0, stream>>>(y, x1, adj, out, E);
    }
}